// Round 7
// baseline (19395.316 us; speedup 1.0000x reference)
//
#include <hip/hip_runtime.h>
#include <hip/hip_fp16.h>
#include <math.h>

// Problem constants (fixed by the reference)
#define B_  32
#define C_  64
#define T_  2048
#define H_  1024

// Recurrence decomposition: 16 groups x 2 batches; 16 WGs (slices) per group
#define NGROUP 16
#define BPG    2
#define NSLICE 16
#define ROWS   64                    // H / NSLICE
#define NWG    (NGROUP * NSLICE)     // 256 WGs == 256 CUs, 1/CU -> co-resident
#define NTHR   512
#define CHUNK  66                    // padded LDS chunk stride (64 + 2 floats)

// d_ws layout:
//   [0, 4096)          : unsigned cnt[1024]; group g's barrier counter at
//                        cnt[g*32] (128B apart). cnt[512] = sink dump (unused)
//   [4096, 4096+128KB) : __half hbuf[2][B_][H_] (ping-pong h exchange, fp16)

__global__ void esn_init_kernel(unsigned* __restrict__ cnt,
                                unsigned* __restrict__ hbuf32) {
    int i = blockIdx.x * blockDim.x + threadIdx.x;
    if (i < 1024) cnt[i] = 0u;
    if (i < 32768) hbuf32[i] = 0u;   // 2*B_*H_ halves = 32768 u32
}

// ---------------------------------------------------------------------------
// x_proj[b,h,t] = bias[h] + sum_c x[b,c,t] * W_in[h,c] -> d_out (B,H,T)
// ---------------------------------------------------------------------------
__global__ __launch_bounds__(256) void esn_xproj_kernel(
        const float* __restrict__ x,
        const float* __restrict__ W_in,
        const float* __restrict__ bias,
        float* __restrict__ out) {
    __shared__ float xs[32 * 256];
    const int tid = threadIdx.x;
    const int t0  = blockIdx.x * 256;
    const int h0  = blockIdx.y * 8;
    const int b   = blockIdx.z;
    const float* xb = x + (size_t)b * C_ * T_ + t0;

    float acc[8];
#pragma unroll
    for (int h = 0; h < 8; ++h) acc[h] = 0.0f;

    for (int ch = 0; ch < 2; ++ch) {
        for (int idx = tid; idx < 32 * 64; idx += 256) {
            const int c  = idx >> 6;
            const int t4 = idx & 63;
            float4 v = *(const float4*)(xb + (size_t)(ch * 32 + c) * T_ + t4 * 4);
            *(float4*)(&xs[c * 256 + t4 * 4]) = v;
        }
        __syncthreads();
        for (int c = 0; c < 32; ++c) {
            const float xv = xs[c * 256 + tid];
#pragma unroll
            for (int h = 0; h < 8; ++h)
                acc[h] = fmaf(xv, W_in[(size_t)(h0 + h) * C_ + ch * 32 + c], acc[h]);
        }
        __syncthreads();
    }

    float* ob = out + (size_t)b * H_ * T_ + t0 + tid;
#pragma unroll
    for (int h = 0; h < 8; ++h)
        ob[(size_t)(h0 + h) * T_] = acc[h] + bias[h0 + h];
}

// ---------------------------------------------------------------------------
// Recurrence. WG wg: group g = wg/16 (batches g*2, g*2+1), slice s = wg%16
// (rows s*64..s*64+63). Thread (cg = lane&15, rt = wave*4 + lane/16) holds
// W_res[s*64+rt*2 + {0,1}][cg*64..cg*64+63] loaded to registers BEFORE the
// t-loop (no __restrict__ -> in-loop reload illegal under possible aliasing
// -> values stay in the unified VGPR/AGPR file; verified rounds 5/6).
//
// Cross-WG exchange: ALL cross-WG data via relaxed AGENT-scope atomic RMWs
// (execute at the LLC = device coherence point; no fences, no wbl2/inv).
// Round-7 change: h exchanged as fp16 (h is tanh-bounded; contraction keeps
// steady-state deviation ~2e-4 rms). Read side: ONE u64 fetch_add(+0) per
// thread = 4 halves. Write side: ONE u32 returning-exchange per row-pair.
// The leak term 0.1*h uses the finalize lane's own UNQUANTIZED f32 state
// kept in registers (same lane owns the same rows every step).
// ---------------------------------------------------------------------------
__global__ __launch_bounds__(NTHR, 2) void esn_recur_kernel(
        const float* W_res,
        float* out,
        unsigned* cnt,
        __half* hbuf) {
    const int wg   = blockIdx.x;
    const int g    = wg >> 4;
    const int s    = wg & 15;
    const int tid  = threadIdx.x;
    const int wave = tid >> 6;
    const int lane = tid & 63;
    const int cg   = lane & 15;                 // col-group: cols cg*64..+63
    const int rt   = (wave << 2) + (lane >> 4); // 0..31 row-pair index
    const int row0 = s * ROWS + rt * 2;
    const int b0   = g * BPG;

    unsigned long long* hb64 = (unsigned long long*)hbuf;
    unsigned*           hb32 = (unsigned*)hbuf;

    // ---- persistent register weights: 2 rows x 16 float4 ----
    float4 w0[16], w1[16];
    {
        const float4* p0 = (const float4*)(W_res + (size_t)row0 * H_) + (cg << 4);
        const float4* p1 = (const float4*)(W_res + (size_t)(row0 + 1) * H_) + (cg << 4);
#pragma unroll
        for (int k = 0; k < 16; ++k) { w0[k] = p0[k]; w1[k] = p1[k]; }
    }

    // h tiles in LDS, padded chunks: col c of batch b at hl[b][(c/64)*66 + c%64]
    __shared__ __align__(16) float hl[BPG][16 * CHUNK];

    // h-fill role: thread loads 4 consecutive h halves (1 u64 RMW)
    const int fb = tid >> 8;                 // batch 0/1
    const int fc = (tid << 2) & 1023;        // col base (multiple of 4)
    float* hlw = &hl[fb][(fc >> 6) * CHUNK + (fc & 63)];

    // finalize role: lanes cg<2 own batch b0+cg, rows (row0, row0+1)
    const bool fin  = (cg < BPG);
    const int  fbat = cg;                    // 0/1 (valid when fin)
    float* op0 = out + ((size_t)(b0 + (fin ? fbat : 0)) * H_ + row0) * (size_t)T_;
    float* op1 = op0 + T_;                   // next row, same batch

    float xp0 = fin ? op0[0] : 0.0f;         // x_proj for step 0
    float xp1 = fin ? op1[0] : 0.0f;
    float hprev0 = 0.0f, hprev1 = 0.0f;      // own rows' exact f32 state

    unsigned sink = 0u;
    unsigned* grpcnt = &cnt[g * 32];

    for (int t = 0; t < T_; ++t) {
        const int p = t & 1;

        // (A) h (fp16) from LLC -> LDS (f32) via ONE u64 fetch_add(+0)
        {
            const size_t i64 = (((size_t)p * B_ + b0 + fb) * H_ + fc) >> 2;
            unsigned long long q = __hip_atomic_fetch_add(
                hb64 + i64, 0ull, __ATOMIC_RELAXED, __HIP_MEMORY_SCOPE_AGENT);
            const unsigned lo = (unsigned)q;
            const unsigned hi = (unsigned)(q >> 32);
            const float2 f0 = __half22float2(__builtin_bit_cast(__half2, lo));
            const float2 f1 = __half22float2(__builtin_bit_cast(__half2, hi));
            *(float4*)hlw = make_float4(f0.x, f0.y, f1.x, f1.y);
        }
        __syncthreads();
        __builtin_amdgcn_sched_barrier(0);

        // prefetch next step's x_proj (plain cached; overlapped with the dot)
        float xp0n = 0.0f, xp1n = 0.0f;
        if (fin && t + 1 < T_) { xp0n = op0[t + 1]; xp1n = op1[t + 1]; }

        // (B) dot: 2 rows x 64 cols x 2 batches, weights from registers
        float s00 = 0.f, s01 = 0.f, s10 = 0.f, s11 = 0.f;  // s[row][batch]
        const float* h0 = &hl[0][cg * CHUNK];
        const float* h1 = &hl[1][cg * CHUNK];
#pragma unroll
        for (int k = 0; k < 16; ++k) {
            const float4 ha  = *(const float4*)(h0 + 4 * k);
            const float4 hb4 = *(const float4*)(h1 + 4 * k);
            const float4 u = w0[k], v = w1[k];
            s00 = fmaf(u.x, ha.x, s00);  s00 = fmaf(u.y, ha.y, s00);
            s00 = fmaf(u.z, ha.z, s00);  s00 = fmaf(u.w, ha.w, s00);
            s10 = fmaf(v.x, ha.x, s10);  s10 = fmaf(v.y, ha.y, s10);
            s10 = fmaf(v.z, ha.z, s10);  s10 = fmaf(v.w, ha.w, s10);
            s01 = fmaf(u.x, hb4.x, s01); s01 = fmaf(u.y, hb4.y, s01);
            s01 = fmaf(u.z, hb4.z, s01); s01 = fmaf(u.w, hb4.w, s01);
            s11 = fmaf(v.x, hb4.x, s11); s11 = fmaf(v.y, hb4.y, s11);
            s11 = fmaf(v.z, hb4.z, s11); s11 = fmaf(v.w, hb4.w, s11);
        }
        // (C) reduce over the 16 cg lanes
#pragma unroll
        for (int m = 1; m <= 8; m <<= 1) {
            s00 += __shfl_xor(s00, m);
            s01 += __shfl_xor(s01, m);
            s10 += __shfl_xor(s10, m);
            s11 += __shfl_xor(s11, m);
        }

        // (D) finalize: lane cg owns batch b0+cg, rows row0 & row0+1
        if (fin) {
            const float sA = fbat ? s01 : s00;   // row0
            const float sB = fbat ? s11 : s10;   // row0+1
            const float pre0 = tanhf(xp0 + sA);
            const float pre1 = tanhf(xp1 + sB);
            const float hn0 = fmaf(0.1f, hprev0, 0.9f * pre0);
            const float hn1 = fmaf(0.1f, hprev1, 0.9f * pre1);
            hprev0 = hn0;
            hprev1 = hn1;
            op0[t] = hn0;                         // plain cached output stores
            op1[t] = hn1;
            const __half2  hp = __floats2half2_rn(hn0, hn1);
            const unsigned pu = __builtin_bit_cast(unsigned, hp);
            const size_t w32 =
                (((size_t)((t + 1) & 1) * B_ + b0 + fbat) * H_ + row0) >> 1;
            // RETURNING swap (sink keeps sc0): ack => executed at LLC
            sink ^= __hip_atomic_exchange(hb32 + w32, pu,
                                          __ATOMIC_RELAXED,
                                          __HIP_MEMORY_SCOPE_AGENT);
        }
        xp0 = xp0n;
        xp1 = xp1n;

        // (E) fence-free group barrier: monotone LLC counter
        if (t + 1 < T_) {
            __syncthreads();   // vmcnt(0): all swaps executed at LLC
            __builtin_amdgcn_sched_barrier(0);
            if (tid == 0) {
                __hip_atomic_fetch_add(grpcnt, 1u, __ATOMIC_RELAXED,
                                       __HIP_MEMORY_SCOPE_AGENT);
                const unsigned tgt = (unsigned)NSLICE * (unsigned)(t + 1);
                while (__hip_atomic_fetch_add(grpcnt, 0u, __ATOMIC_RELAXED,
                                              __HIP_MEMORY_SCOPE_AGENT) < tgt) {
                    __builtin_amdgcn_s_sleep(1);
                }
            }
            __syncthreads();
            __builtin_amdgcn_sched_barrier(0);
        }
    }

    // keep the swap returns live (forces the returning/sc0 form)
    if (sink == 0xDEADBEEFu && tid == 0) cnt[512] = 1u;
}

extern "C" void kernel_launch(void* const* d_in, const int* in_sizes, int n_in,
                              void* d_out, int out_size, void* d_ws, size_t ws_size,
                              hipStream_t stream) {
    const float* x     = (const float*)d_in[0];   // (B, C, T)
    const float* W_in  = (const float*)d_in[1];   // (H, C)
    const float* W_res = (const float*)d_in[2];   // (H, H)
    const float* bias  = (const float*)d_in[3];   // (H,)
    float* out = (float*)d_out;                   // (B, H, T)

    unsigned* cnt  = (unsigned*)d_ws;
    __half*   hbuf = (__half*)((char*)d_ws + 4096);

    esn_init_kernel<<<256, 256, 0, stream>>>(cnt, (unsigned*)hbuf);

    dim3 g1(T_ / 256, H_ / 8, B_);
    esn_xproj_kernel<<<g1, 256, 0, stream>>>(x, W_in, bias, out);

    esn_recur_kernel<<<NWG, NTHR, 0, stream>>>(W_res, out, cnt, hbuf);
}